// Round 1
// 345.875 us; speedup vs baseline: 1.1613x; 1.1613x over previous
//
#include <hip/hip_runtime.h>
#include <stdint.h>

typedef unsigned long long u64;

// Problem constants
constexpr int C      = 256;          // channels (in == out)
constexpr int H      = 28, W = 28;
constexpr int HW     = H * W;        // 784
constexpr int NB     = 64;           // batch
constexpr int WORDS  = 4;            // 256 / 64 bits
constexpr int CNT    = NB * HW;      // per-channel reduction count = 50176
constexpr int TOTAL  = NB * C * HW;  // 12,845,056
constexpr int COT    = 16;           // output-channel tile per block (R6: 8 -> 16)
constexpr int TW     = 30;           // padded tile width (28 + 2)
constexpr int TP     = TW * TW;      // 900 padded pixels

// ---------------------------------------------------------------------------
// Pack weight signs, co-major within each COT-channel group:
//   wb[(((co/COT)*9 + tap)*COT + co%COT)*4 + wd]
// plus P[co*9+tap] = popcount of the 256 weight sign bits for that tap
// (zero-padded-border correction).
// R6: ballot-based — one WAVE per (co,tap), lane j supplies bit j of each
// word via __ballot. Old version: 2304 threads x 1024 dependent strided
// loads = hidden latency-bound kernel. Now 147K threads x 4 loads.
// ---------------------------------------------------------------------------
__global__ void pack_w_kernel(const float* __restrict__ w, uint64_t* __restrict__ wb,
                              int* __restrict__ P) {
    int gw   = (blockIdx.x * blockDim.x + threadIdx.x) >> 6;  // wave id = co*9 + tap
    int lane = threadIdx.x & 63;
    if (gw >= C * 9) return;
    int tap = gw % 9;
    int co  = gw / 9;
    const float* base = w + (size_t)co * C * 9 + tap;
    uint64_t* dst = wb + (size_t)(((co / COT) * 9 + tap) * COT + (co % COT)) * WORDS;
    int ptot = 0;
#pragma unroll
    for (int wd = 0; wd < WORDS; ++wd) {
        float v = base[(size_t)(wd * 64 + lane) * 9];
        u64 bits = __ballot(v < 0.f);
        if (lane == 0) dst[wd] = bits;
        ptot += __popcll(bits);
    }
    if (lane == 0) P[gw] = ptot;
}

// ---------------------------------------------------------------------------
// Pack activation signs: x[n][c][h][w] -> xb[n][p][wd]  (p = h*W+w)
// ---------------------------------------------------------------------------
__global__ void pack_x_kernel(const float* __restrict__ x, uint64_t* __restrict__ xb) {
    int t = blockIdx.x * blockDim.x + threadIdx.x;  // n*HW + p
    if (t >= NB * HW) return;
    int n = t / HW, p = t % HW;
    const float* base = x + (size_t)n * C * HW + p;
    uint64_t* dst = xb + (size_t)t * WORDS;
#pragma unroll
    for (int wd = 0; wd < WORDS; ++wd) {
        uint64_t bits = 0;
#pragma unroll 8
        for (int j = 0; j < 64; ++j) {
            if (base[(size_t)(wd * 64 + j) * HW] < 0.f) bits |= (1ull << j);
        }
        dst[wd] = bits;
    }
}

// ---------------------------------------------------------------------------
// Fused BN(scale/shift) + binarize + pack (y1 stored as i16).
// sign(clip(z)) == sign(z), binarize(0)=+1, so only the sign of z matters.
// ---------------------------------------------------------------------------
__global__ void bn_signpack_kernel(const short* __restrict__ y,
                                   const float* __restrict__ scale,
                                   const float* __restrict__ shift,
                                   uint64_t* __restrict__ xb) {
    int t = blockIdx.x * blockDim.x + threadIdx.x;
    if (t >= NB * HW) return;
    int n = t / HW, p = t % HW;
    const short* base = y + (size_t)n * C * HW + p;
    uint64_t* dst = xb + (size_t)t * WORDS;
#pragma unroll
    for (int wd = 0; wd < WORDS; ++wd) {
        uint64_t bits = 0;
#pragma unroll 8
        for (int j = 0; j < 64; ++j) {
            int c = wd * 64 + j;
            float z = (float)base[(size_t)c * HW] * scale[c] + shift[c];
            if (z < 0.f) bits |= (1ull << j);
        }
        dst[wd] = bits;
    }
}

// ---------------------------------------------------------------------------
// Binary conv 3x3 pad=1, XNOR+popcount.
// R5: no private arrays — named scalars via token-pasting macros (SROA runs
// before late unrolling; arrays -> scratch). Border fixup via LDS table Tl.
// R6 theory: bconv was LDS-issue/latency-bound, not VALU-bound.
//   (a) weights now loaded per-tap from GLOBAL with wave-uniform addresses
//       -> s_load into SGPRs; wl LDS stage and its 16 ds_read_b128/tap/wave
//       are gone. v_xor_b32 takes the SGPR operand directly.
//   (b) COT 8 -> 16 (two SGPR-safe halves of 8 per tap): the x-tile LDS
//       reads feed 2x the channels; per-block fixed costs amortize 2x.
// Tap-outer `#pragma unroll 1` keeps the weight live-set at 32 u64 = 64 SGPR.
// ---------------------------------------------------------------------------

// weights (SGPR-resident): w{c}{wd} for local c=0..7 of the current half
#define W_DECLS u64 w00,w01,w02,w03, w10,w11,w12,w13, w20,w21,w22,w23, \
                    w30,w31,w32,w33, w40,w41,w42,w43, w50,w51,w52,w53, \
                    w60,w61,w62,w63, w70,w71,w72,w73;
#define W_LOADS(b) \
    w00=(b)[0];  w01=(b)[1];  w02=(b)[2];  w03=(b)[3];  \
    w10=(b)[4];  w11=(b)[5];  w12=(b)[6];  w13=(b)[7];  \
    w20=(b)[8];  w21=(b)[9];  w22=(b)[10]; w23=(b)[11]; \
    w30=(b)[12]; w31=(b)[13]; w32=(b)[14]; w33=(b)[15]; \
    w40=(b)[16]; w41=(b)[17]; w42=(b)[18]; w43=(b)[19]; \
    w50=(b)[20]; w51=(b)[21]; w52=(b)[22]; w53=(b)[23]; \
    w60=(b)[24]; w61=(b)[25]; w62=(b)[26]; w63=(b)[27]; \
    w70=(b)[28]; w71=(b)[29]; w72=(b)[30]; w73=(b)[31];

// accumulators a{r}_{co}, co = 0..15
#define A_DECL(r) int a##r##_0=0,a##r##_1=0,a##r##_2=0,a##r##_3=0, \
                      a##r##_4=0,a##r##_5=0,a##r##_6=0,a##r##_7=0, \
                      a##r##_8=0,a##r##_9=0,a##r##_10=0,a##r##_11=0, \
                      a##r##_12=0,a##r##_13=0,a##r##_14=0,a##r##_15=0;

// x fragments x{r}{wd} from LDS
#define XD(r) const u64 x##r##0 = xl[qb##r + dq],        x##r##1 = xl[TP + qb##r + dq], \
              x##r##2 = xl[2*TP + qb##r + dq],           x##r##3 = xl[3*TP + qb##r + dq];

#define ACC1(r,c,g) a##r##_##g += __popcll(x##r##0 ^ w##c##0) + __popcll(x##r##1 ^ w##c##1) \
                                + __popcll(x##r##2 ^ w##c##2) + __popcll(x##r##3 ^ w##c##3);
#define ACC_H0(r) ACC1(r,0,0) ACC1(r,1,1) ACC1(r,2,2) ACC1(r,3,3) \
                  ACC1(r,4,4) ACC1(r,5,5) ACC1(r,6,6) ACC1(r,7,7)
#define ACC_H1(r) ACC1(r,0,8)  ACC1(r,1,9)  ACC1(r,2,10) ACC1(r,3,11) \
                  ACC1(r,4,12) ACC1(r,5,13) ACC1(r,6,14) ACC1(r,7,15)

#define EPI1(r, co) { \
    float y = (float)(Tl[mk + co] - 2 * a##r##_##co); \
    const size_t oidx = obase_n + (size_t)(co) * HW + pp; \
    if (HAS_RES) y += residual[oidx]; \
    yout[oidx] = (OUT_T)y; \
    sy##co += y; sq##co += y * y; }
#define EPI_R(r) { const int pp = t + 256 * (r); \
    const int oh = pp / W, ow = pp - oh * W; \
    const int mk = (((oh==0)?0:((oh==H-1)?2:1))*3 + ((ow==0)?0:((ow==W-1)?2:1))) * COT; \
    EPI1(r,0)  EPI1(r,1)  EPI1(r,2)  EPI1(r,3)  EPI1(r,4)  EPI1(r,5)  EPI1(r,6)  EPI1(r,7) \
    EPI1(r,8)  EPI1(r,9)  EPI1(r,10) EPI1(r,11) EPI1(r,12) EPI1(r,13) EPI1(r,14) EPI1(r,15) }

#define RED(c) { float s1 = sy##c, s2 = sq##c; \
    _Pragma("unroll") \
    for (int off = 32; off; off >>= 1) { s1 += __shfl_down(s1, off); s2 += __shfl_down(s2, off); } \
    if (lane == 0) { red[wave*32 + c] = s1; red[wave*32 + 16 + c] = s2; } }

template<bool HAS_RES, typename OUT_T>
__launch_bounds__(256, 3)
__global__ void bconv_kernel(const uint64_t* __restrict__ xb,
                             const uint64_t* __restrict__ wb,
                             const int* __restrict__ P,
                             const float* __restrict__ residual,
                             OUT_T* __restrict__ yout,
                             double* __restrict__ sum, double* __restrict__ sumsq) {
    __shared__ alignas(16) uint64_t xl[WORDS * TP];   // 28800 B, SoA
    __shared__ int Tl[9 * COT];                       // border-corrected base per (mask,co)
    __shared__ float red[128];

    const int n  = blockIdx.x;
    const int cg = blockIdx.y;   // channel group (16 channels)
    const int t  = threadIdx.x;

    // zero padded tile, then scatter interior (bit=0 encodes +1; border reads
    // as "all +1" and is corrected exactly via Tl)
    for (int i = t; i < WORDS * TP; i += 256) xl[i] = 0;
    __syncthreads();
    const uint64_t* xsrc = xb + (size_t)n * HW * WORDS;
    for (int i = t; i < HW * WORDS; i += 256) {
        int wd = i & 3, p = i >> 2;
        int q = (p / W) * TW + (p % W) + TW + 1;
        xl[wd * TP + q] = xsrc[i];
    }
    // Tl[mask*COT+co] = 9*256 - sum over taps invalid for this border-mask of
    // (256 - 2*P[co][tap]); mask = mrow*3+mcol, mrow/mcol in {0:first,1:mid,2:last}
    if (t < 9 * COT) {   // 144 entries
        const int co = t / 9, mask = t % 9;
        const int mr = mask / 3, mc = mask % 3;
        const int* Pg = P + cg * (COT * 9) + co * 9;
        int val = 9 * 256;
        for (int kh = 0; kh < 3; ++kh)
            for (int kw = 0; kw < 3; ++kw) {
                bool inv = (mr == 0 && kh == 0) || (mr == 2 && kh == 2) ||
                           (mc == 0 && kw == 0) || (mc == 2 && kw == 2);
                if (inv) val -= (256 - 2 * Pg[kh * 3 + kw]);
            }
        Tl[mask * COT + co] = val;
    }
    __syncthreads();

    // pixel assignment: p_r = t + 256*r; r=0..2 always valid, r=3 iff t<16
    const int p0 = t, p1 = t + 256, p2 = t + 512, p3 = t + 768;
    const int qb0 = (p0 / W) * TW + (p0 % W);
    const int qb1 = (p1 / W) * TW + (p1 % W);
    const int qb2 = (p2 / W) * TW + (p2 % W);
    const int qb3 = (t < 16) ? ((p3 / W) * TW + (p3 % W)) : 0;

    A_DECL(0) A_DECL(1) A_DECL(2) A_DECL(3)

    const uint64_t* wgb = wb + (size_t)cg * (9 * COT * WORDS);   // wave-uniform

#pragma unroll 1   // keep taps a real loop — weight live-set stays 32 u64 (64 SGPR)
    for (int tap = 0; tap < 9; ++tap) {
        const uint64_t* wt = wgb + tap * (COT * WORDS);   // uniform -> s_load
        const int dq = (tap / 3) * TW + (tap % 3);
        XD(0) XD(1) XD(2)
        u64 x30 = 0, x31 = 0, x32 = 0, x33 = 0;
        if (t < 16) {
            const int q3 = qb3 + dq;
            x30 = xl[q3]; x31 = xl[TP + q3]; x32 = xl[2*TP + q3]; x33 = xl[3*TP + q3];
        }
        {   // half 0: output channels cg*16 + 0..7
            W_DECLS W_LOADS(wt)
            ACC_H0(0) ACC_H0(1) ACC_H0(2)
            if (t < 16) { ACC_H0(3) }
        }
        {   // half 1: output channels cg*16 + 8..15
            W_DECLS W_LOADS(wt + 32)
            ACC_H1(0) ACC_H1(1) ACC_H1(2)
            if (t < 16) { ACC_H1(3) }
        }
    }

    // ---- epilogue: table-corrected store + stats, all named scalars ----
    float sy0=0,sy1=0,sy2=0,sy3=0,sy4=0,sy5=0,sy6=0,sy7=0;
    float sy8=0,sy9=0,sy10=0,sy11=0,sy12=0,sy13=0,sy14=0,sy15=0;
    float sq0=0,sq1=0,sq2=0,sq3=0,sq4=0,sq5=0,sq6=0,sq7=0;
    float sq8=0,sq9=0,sq10=0,sq11=0,sq12=0,sq13=0,sq14=0,sq15=0;
    const size_t obase_n = ((size_t)n * C + (size_t)cg * COT) * HW;

    EPI_R(0) EPI_R(1) EPI_R(2)
    if (t < 16) { EPI_R(3) }

    // block reduction of 16 channel sums + 16 sumsq
    const int lane = t & 63, wave = t >> 6;
    RED(0)  RED(1)  RED(2)  RED(3)  RED(4)  RED(5)  RED(6)  RED(7)
    RED(8)  RED(9)  RED(10) RED(11) RED(12) RED(13) RED(14) RED(15)
    __syncthreads();
    if (t < 32) {
        double tot = (double)red[t] + (double)red[32 + t]
                   + (double)red[64 + t] + (double)red[96 + t];
        if (t < 16) atomicAdd(&sum[cg * COT + t], tot);
        else        atomicAdd(&sumsq[cg * COT + t - 16], tot);
    }
}

// ---------------------------------------------------------------------------
// BN stats -> per-channel scale/shift (fp64 internally)
// ---------------------------------------------------------------------------
__global__ void finalize_kernel(const double* __restrict__ sum,
                                const double* __restrict__ sumsq,
                                const float* __restrict__ gamma,
                                const float* __restrict__ beta,
                                float* __restrict__ scale,
                                float* __restrict__ shift) {
    int c = threadIdx.x;  // 256 threads
    double mean = sum[c] / (double)CNT;
    double var  = sumsq[c] / (double)CNT - mean * mean;
    double inv  = 1.0 / sqrt(var + 1e-5);
    float sc = (float)inv * gamma[c];
    scale[c] = sc;
    shift[c] = beta[c] - (float)(mean * inv) * gamma[c];
}

// ---------------------------------------------------------------------------
// Final: out = clip(z*scale[c] + shift[c], -1, 1), float4 vectorized
// ---------------------------------------------------------------------------
__global__ void bn_clip_kernel(const float4* __restrict__ z,
                               const float* __restrict__ scale,
                               const float* __restrict__ shift,
                               float4* __restrict__ out, int total4) {
    for (int i = blockIdx.x * blockDim.x + threadIdx.x; i < total4;
         i += gridDim.x * blockDim.x) {
        int c = (i / (HW / 4)) & (C - 1);
        float s = scale[c], b = shift[c];
        float4 v = z[i];
        v.x = fminf(1.f, fmaxf(-1.f, v.x * s + b));
        v.y = fminf(1.f, fmaxf(-1.f, v.y * s + b));
        v.z = fminf(1.f, fmaxf(-1.f, v.z * s + b));
        v.w = fminf(1.f, fmaxf(-1.f, v.w * s + b));
        out[i] = v;
    }
}

// ---------------------------------------------------------------------------
extern "C" void kernel_launch(void* const* d_in, const int* in_sizes, int n_in,
                              void* d_out, int out_size, void* d_ws, size_t ws_size,
                              hipStream_t stream) {
    const float* x  = (const float*)d_in[0];
    const float* w1 = (const float*)d_in[1];
    const float* w2 = (const float*)d_in[2];
    const float* g1 = (const float*)d_in[3];
    const float* b1 = (const float*)d_in[4];
    const float* g2 = (const float*)d_in[5];
    const float* b2 = (const float*)d_in[6];
    float* out = (float*)d_out;

    char* ws = (char*)d_ws;
    size_t off = 0;
    float* z2 = (float*)(ws + off);          off += (size_t)TOTAL * 4;            // 51.4 MB
    uint64_t* xb1 = (uint64_t*)(ws + off);   off += (size_t)NB * HW * WORDS * 8;  // 1.6 MB
    uint64_t* xb2 = (uint64_t*)(ws + off);   off += (size_t)NB * HW * WORDS * 8;
    uint64_t* wb1 = (uint64_t*)(ws + off);   off += (size_t)C * 9 * WORDS * 8;    // 73 KB
    uint64_t* wb2 = (uint64_t*)(ws + off);   off += (size_t)C * 9 * WORDS * 8;
    int* P1 = (int*)(ws + off);              off += (size_t)C * 9 * 4;
    int* P2 = (int*)(ws + off);              off += (size_t)C * 9 * 4;
    double* stats = (double*)(ws + off);     off += 4 * 256 * 8;
    double* sum1 = stats, *sumsq1 = stats + 256, *sum2 = stats + 512, *sumsq2 = stats + 768;
    float* coefs = (float*)(ws + off);       off += 4 * 256 * 4;
    float* scale1 = coefs, *shift1 = coefs + 256, *scale2 = coefs + 512, *shift2 = coefs + 768;

    // y1 (i16) lives in d_out as scratch; fully rewritten by bn_clip at the end
    short* y1 = (short*)d_out;

    // zero the fp64 stat accumulators (ws is re-poisoned before every launch)
    hipMemsetAsync(stats, 0, 4 * 256 * 8, stream);

    // pack weights (one wave per (co,tap)) + input signs
    pack_w_kernel<<<(C * 9 * 64 + 255) / 256, 256, 0, stream>>>(w1, wb1, P1);
    pack_w_kernel<<<(C * 9 * 64 + 255) / 256, 256, 0, stream>>>(w2, wb2, P2);
    pack_x_kernel<<<(NB * HW + 255) / 256, 256, 0, stream>>>(x, xb1);

    dim3 cgrid(NB, C / COT);
    // conv1: y1 (i16) -> d_out scratch, fused BN1 stats
    bconv_kernel<false, short><<<cgrid, 256, 0, stream>>>(xb1, wb1, P1, nullptr, y1, sum1, sumsq1);
    finalize_kernel<<<1, 256, 0, stream>>>(sum1, sumsq1, g1, b1, scale1, shift1);
    // BN1 + hardtanh + binarize collapse to sign(BN1) -> bit-pack
    bn_signpack_kernel<<<(NB * HW + 255) / 256, 256, 0, stream>>>(y1, scale1, shift1, xb2);
    // conv2 + residual, fused BN2 stats, z2 -> ws
    bconv_kernel<true, float><<<cgrid, 256, 0, stream>>>(xb2, wb2, P2, x, z2, sum2, sumsq2);
    finalize_kernel<<<1, 256, 0, stream>>>(sum2, sumsq2, g2, b2, scale2, shift2);
    // BN2 + hardtanh -> out
    bn_clip_kernel<<<4096, 256, 0, stream>>>((const float4*)z2, scale2, shift2,
                                             (float4*)out, TOTAL / 4);
}

// Round 2
// 344.969 us; speedup vs baseline: 1.1644x; 1.0026x over previous
//
#include <hip/hip_runtime.h>
#include <stdint.h>

typedef unsigned long long u64;

// Problem constants
constexpr int C      = 256;          // channels (in == out)
constexpr int H      = 28, W = 28;
constexpr int HW     = H * W;        // 784
constexpr int NB     = 64;           // batch
constexpr int WORDS  = 4;            // 256 / 64 bits
constexpr int CNT    = NB * HW;      // per-channel reduction count = 50176
constexpr int TOTAL  = NB * C * HW;  // 12,845,056
constexpr int COT    = 16;           // output-channel tile per block
constexpr int TW     = 30;           // padded tile width (28 + 2)
// R7: pixel-split — each block handles RH=14 output rows (half the image)
constexpr int RH     = 14;           // output rows per block
constexpr int TRH    = 16;           // tile rows incl. halo
constexpr int TPH    = TRH * TW;     // 480 padded tile positions

// ---------------------------------------------------------------------------
// R7 merged pre-pass: one kernel does BOTH weight packs (ballot, one wave per
// (co,tap)), the activation pack, and zeroes the fp64 stat accumulators.
// Replaces 3 kernels + 1 memset -> 1 dispatch.
// wb layout co-major per group: wb[(((co/COT)*9+tap)*COT + co%COT)*4 + wd]
// ---------------------------------------------------------------------------
__global__ void pack_all_kernel(const float* __restrict__ w1, const float* __restrict__ w2,
                                const float* __restrict__ x,
                                uint64_t* __restrict__ wb1, uint64_t* __restrict__ wb2,
                                int* __restrict__ P1, int* __restrict__ P2,
                                uint64_t* __restrict__ xb, double* __restrict__ stats) {
    const int t = threadIdx.x;
    if (blockIdx.x < 1152) {            // 1152 blocks * 4 waves = 4608 = 2*2304
        const int wv   = blockIdx.x * 4 + (t >> 6);   // global wave id
        const int lane = t & 63;
        const bool second = (wv >= C * 9);
        const float* w = second ? w2 : w1;
        uint64_t* wb   = second ? wb2 : wb1;
        int* P         = second ? P2 : P1;
        const int g    = second ? wv - C * 9 : wv;    // co*9 + tap
        const int tap = g % 9, co = g / 9;
        const float* base = w + (size_t)co * C * 9 + tap;
        uint64_t* dst = wb + (size_t)(((co / COT) * 9 + tap) * COT + (co % COT)) * WORDS;
        int ptot = 0;
#pragma unroll
        for (int wd = 0; wd < WORDS; ++wd) {
            float v = base[(size_t)(wd * 64 + lane) * 9];
            u64 bits = __ballot(v < 0.f);
            if (lane == 0) dst[wd] = bits;
            ptot += __popcll(bits);
        }
        if (lane == 0) P[g] = ptot;
    } else {
        const int gid = (blockIdx.x - 1152) * 256 + t;   // 196 blocks -> 50176 exact
        if (gid < 1024) stats[gid] = 0.0;                // zero sum1/sumsq1/sum2/sumsq2
        const int n = gid / HW, p = gid % HW;
        const float* base = x + (size_t)n * C * HW + p;
        uint64_t* dst = xb + (size_t)gid * WORDS;
#pragma unroll
        for (int wd = 0; wd < WORDS; ++wd) {
            uint64_t bits = 0;
#pragma unroll 8
            for (int j = 0; j < 64; ++j) {
                if (base[(size_t)(wd * 64 + j) * HW] < 0.f) bits |= (1ull << j);
            }
            dst[wd] = bits;
        }
    }
}

// ---------------------------------------------------------------------------
// Fused finalize (redundant per block) + BN + binarize + pack (y1 as i16).
// sign(clip(z)) == sign(z), binarize(0)=+1, so only the sign of z matters.
// ---------------------------------------------------------------------------
__global__ void bn_signpack_kernel(const short* __restrict__ y,
                                   const double* __restrict__ sum,
                                   const double* __restrict__ sumsq,
                                   const float* __restrict__ gamma,
                                   const float* __restrict__ beta,
                                   uint64_t* __restrict__ xb) {
    __shared__ float s_scale[C], s_shift[C];
    const int t = threadIdx.x;
    {   // inline finalize: 256 threads = 256 channels
        double mean = sum[t] / (double)CNT;
        double var  = sumsq[t] / (double)CNT - mean * mean;
        double inv  = 1.0 / sqrt(var + 1e-5);
        float sc = (float)inv * gamma[t];
        s_scale[t] = sc;
        s_shift[t] = beta[t] - (float)(mean * inv) * gamma[t];
    }
    __syncthreads();
    const int gid = blockIdx.x * blockDim.x + t;
    if (gid >= NB * HW) return;
    const int n = gid / HW, p = gid % HW;
    const short* base = y + (size_t)n * C * HW + p;
    uint64_t* dst = xb + (size_t)gid * WORDS;
#pragma unroll
    for (int wd = 0; wd < WORDS; ++wd) {
        uint64_t bits = 0;
#pragma unroll 8
        for (int j = 0; j < 64; ++j) {
            int c = wd * 64 + j;
            float z = (float)base[(size_t)c * HW] * s_scale[c] + s_shift[c];
            if (z < 0.f) bits |= (1ull << j);
        }
        dst[wd] = bits;
    }
}

// ---------------------------------------------------------------------------
// Binary conv 3x3 pad=1, XNOR+popcount.
// R5: no private arrays — named scalars via macros (SROA runs before late
//     unrolling; arrays -> scratch). Border fixup via LDS table Tl.
// R6: weights from GLOBAL with wave-uniform addresses -> SGPRs; COT=16.
// R7: pixel-split. R6 post-mortem: occupancy FELL to 24.6% (grid 1024 = 4
//     blocks/CU; ~2 waves/SIMD resident -> per-tap s_load lgkm waits exposed,
//     VALUBusy stuck at 68%). Split each image into 2 row-halves: grid 2048,
//     accs 64->32 ints, LDS 30.2K->15.7K, live set ~70 VGPR -> many more
//     waves/SIMD; same total VALU work.
// ---------------------------------------------------------------------------

#define W_DECLS u64 w00,w01,w02,w03, w10,w11,w12,w13, w20,w21,w22,w23, \
                    w30,w31,w32,w33, w40,w41,w42,w43, w50,w51,w52,w53, \
                    w60,w61,w62,w63, w70,w71,w72,w73;
#define W_LOADS(b) \
    w00=(b)[0];  w01=(b)[1];  w02=(b)[2];  w03=(b)[3];  \
    w10=(b)[4];  w11=(b)[5];  w12=(b)[6];  w13=(b)[7];  \
    w20=(b)[8];  w21=(b)[9];  w22=(b)[10]; w23=(b)[11]; \
    w30=(b)[12]; w31=(b)[13]; w32=(b)[14]; w33=(b)[15]; \
    w40=(b)[16]; w41=(b)[17]; w42=(b)[18]; w43=(b)[19]; \
    w50=(b)[20]; w51=(b)[21]; w52=(b)[22]; w53=(b)[23]; \
    w60=(b)[24]; w61=(b)[25]; w62=(b)[26]; w63=(b)[27]; \
    w70=(b)[28]; w71=(b)[29]; w72=(b)[30]; w73=(b)[31];

// accumulators a{r}_{co}, r = 0..1, co = 0..15
#define A_DECL(r) int a##r##_0=0,a##r##_1=0,a##r##_2=0,a##r##_3=0, \
                      a##r##_4=0,a##r##_5=0,a##r##_6=0,a##r##_7=0, \
                      a##r##_8=0,a##r##_9=0,a##r##_10=0,a##r##_11=0, \
                      a##r##_12=0,a##r##_13=0,a##r##_14=0,a##r##_15=0;

#define ACC1(r,c,g) a##r##_##g += __popcll(x##r##0 ^ w##c##0) + __popcll(x##r##1 ^ w##c##1) \
                                + __popcll(x##r##2 ^ w##c##2) + __popcll(x##r##3 ^ w##c##3);
#define ACC_H0(r) ACC1(r,0,0) ACC1(r,1,1) ACC1(r,2,2) ACC1(r,3,3) \
                  ACC1(r,4,4) ACC1(r,5,5) ACC1(r,6,6) ACC1(r,7,7)
#define ACC_H1(r) ACC1(r,0,8)  ACC1(r,1,9)  ACC1(r,2,10) ACC1(r,3,11) \
                  ACC1(r,4,12) ACC1(r,5,13) ACC1(r,6,14) ACC1(r,7,15)

#define EPI1(r, co) { \
    float yv = (float)(Tl[mk + co] - 2 * a##r##_##co); \
    const size_t oidx = obase_n + (size_t)(co) * HW + pp; \
    if (HAS_RES) yv += residual[oidx]; \
    yout[oidx] = (OUT_T)yv; \
    sy##co += yv; sq##co += yv * yv; }
#define EPI_R(r) { const int lp = t + 256 * (r); \
    const int lr = lp / W, ow = lp - lr * W; \
    const int oh = ph * RH + lr; \
    const int pp = oh * W + ow; \
    const int mk = (((oh==0)?0:((oh==H-1)?2:1))*3 + ((ow==0)?0:((ow==W-1)?2:1))) * COT; \
    EPI1(r,0)  EPI1(r,1)  EPI1(r,2)  EPI1(r,3)  EPI1(r,4)  EPI1(r,5)  EPI1(r,6)  EPI1(r,7) \
    EPI1(r,8)  EPI1(r,9)  EPI1(r,10) EPI1(r,11) EPI1(r,12) EPI1(r,13) EPI1(r,14) EPI1(r,15) }

#define RED(c) { float s1 = sy##c, s2 = sq##c; \
    _Pragma("unroll") \
    for (int off = 32; off; off >>= 1) { s1 += __shfl_down(s1, off); s2 += __shfl_down(s2, off); } \
    if (lane == 0) { red[wave*32 + c] = s1; red[wave*32 + 16 + c] = s2; } }

template<bool HAS_RES, typename OUT_T>
__launch_bounds__(256, 4)
__global__ void bconv_kernel(const uint64_t* __restrict__ xb,
                             const uint64_t* __restrict__ wb,
                             const int* __restrict__ P,
                             const float* __restrict__ residual,
                             OUT_T* __restrict__ yout,
                             double* __restrict__ sum, double* __restrict__ sumsq) {
    __shared__ alignas(16) uint64_t xl[WORDS * TPH];  // 15360 B, SoA halves
    __shared__ int Tl[9 * COT];
    __shared__ float red[128];

    const int n  = blockIdx.x >> 1;
    const int ph = blockIdx.x & 1;   // row-half: rows [ph*14, ph*14+13]
    const int cg = blockIdx.y;       // channel group (16 channels)
    const int t  = threadIdx.x;

    // zero padded half-tile, then scatter the 15 needed input rows
    for (int i = t; i < WORDS * TPH; i += 256) xl[i] = 0;
    __syncthreads();
    const uint64_t* xsrc = xb + (size_t)n * HW * WORDS;
    // rows gr0..gr0+14 land at tile rows tr0..tr0+14  (ph=0: gr0=0,tr0=1;
    // ph=1: gr0=13,tr0=0). tile row tr <-> global row (ph*RH-1)+tr.
    const int gr0 = ph ? RH - 1 : 0;
    const int tr0 = ph ? 0 : 1;
    for (int i = t; i < 15 * W * WORDS; i += 256) {   // 1680
        int wd = i & 3, p = i >> 2;                   // p: local (row,col)
        int lr = p / W, col = p - lr * W;
        int q = (tr0 + lr) * TW + col + 1;
        xl[wd * TPH + q] = xsrc[(size_t)gr0 * W * WORDS + i];
    }
    // Tl[mask*COT+co]: border-corrected base (zero rows/cols read as "+1",
    // corrected exactly per border mask)
    if (t < 9 * COT) {   // 144 entries
        const int co = t / 9, mask = t % 9;
        const int mr = mask / 3, mc = mask % 3;
        const int* Pg = P + cg * (COT * 9) + co * 9;
        int val = 9 * 256;
        for (int kh = 0; kh < 3; ++kh)
            for (int kw = 0; kw < 3; ++kw) {
                bool inv = (mr == 0 && kh == 0) || (mr == 2 && kh == 2) ||
                           (mc == 0 && kw == 0) || (mc == 2 && kw == 2);
                if (inv) val -= (256 - 2 * Pg[kh * 3 + kw]);
            }
        Tl[mask * COT + co] = val;
    }
    __syncthreads();

    // pixel assignment: local pixel lp_r = t + 256*r; r=0 always, r=1 iff t<136
    const int lr0 = t / W, lc0 = t - lr0 * W;
    const int qb0 = lr0 * TW + lc0;                  // window top-left in tile
    const int lp1 = t + 256;
    const int lr1 = lp1 / W, lc1 = lp1 - lr1 * W;
    const int qb1 = (t < 136) ? lr1 * TW + lc1 : 0;  // clamped: safe dummy reads

    A_DECL(0) A_DECL(1)

    const uint64_t* wgb = wb + (size_t)cg * (9 * COT * WORDS);   // wave-uniform

#pragma unroll 1   // keep taps a real loop — weight live-set stays 32 u64 (64 SGPR)
    for (int tap = 0; tap < 9; ++tap) {
        const uint64_t* wt = wgb + tap * (COT * WORDS);   // uniform -> s_load
        const int dq = (tap / 3) * TW + (tap % 3);
        const int q0 = qb0 + dq;
        const u64 x00 = xl[q0], x01 = xl[TPH + q0], x02 = xl[2*TPH + q0], x03 = xl[3*TPH + q0];
        const int q1 = qb1 + dq;
        const u64 x10 = xl[q1], x11 = xl[TPH + q1], x12 = xl[2*TPH + q1], x13 = xl[3*TPH + q1];
        {   // half 0: output channels cg*16 + 0..7
            W_DECLS W_LOADS(wt)
            ACC_H0(0)
            if (t < 136) { ACC_H0(1) }
        }
        {   // half 1: output channels cg*16 + 8..15
            W_DECLS W_LOADS(wt + 32)
            ACC_H1(0)
            if (t < 136) { ACC_H1(1) }
        }
    }

    // ---- epilogue: table-corrected store + stats, all named scalars ----
    float sy0=0,sy1=0,sy2=0,sy3=0,sy4=0,sy5=0,sy6=0,sy7=0;
    float sy8=0,sy9=0,sy10=0,sy11=0,sy12=0,sy13=0,sy14=0,sy15=0;
    float sq0=0,sq1=0,sq2=0,sq3=0,sq4=0,sq5=0,sq6=0,sq7=0;
    float sq8=0,sq9=0,sq10=0,sq11=0,sq12=0,sq13=0,sq14=0,sq15=0;
    const size_t obase_n = ((size_t)n * C + (size_t)cg * COT) * HW;

    EPI_R(0)
    if (t < 136) { EPI_R(1) }

    // block reduction of 16 channel sums + 16 sumsq
    const int lane = t & 63, wave = t >> 6;
    RED(0)  RED(1)  RED(2)  RED(3)  RED(4)  RED(5)  RED(6)  RED(7)
    RED(8)  RED(9)  RED(10) RED(11) RED(12) RED(13) RED(14) RED(15)
    __syncthreads();
    if (t < 32) {
        double tot = (double)red[t] + (double)red[32 + t]
                   + (double)red[64 + t] + (double)red[96 + t];
        if (t < 16) atomicAdd(&sum[cg * COT + t], tot);
        else        atomicAdd(&sumsq[cg * COT + t - 16], tot);
    }
}

// ---------------------------------------------------------------------------
// Final: fused finalize (redundant per block) + out = clip(z*s+b, -1, 1)
// ---------------------------------------------------------------------------
__global__ void bn_clip_kernel(const float4* __restrict__ z,
                               const double* __restrict__ sum,
                               const double* __restrict__ sumsq,
                               const float* __restrict__ gamma,
                               const float* __restrict__ beta,
                               float4* __restrict__ out, int total4) {
    __shared__ float s_scale[C], s_shift[C];
    const int t = threadIdx.x;
    {
        double mean = sum[t] / (double)CNT;
        double var  = sumsq[t] / (double)CNT - mean * mean;
        double inv  = 1.0 / sqrt(var + 1e-5);
        float sc = (float)inv * gamma[t];
        s_scale[t] = sc;
        s_shift[t] = beta[t] - (float)(mean * inv) * gamma[t];
    }
    __syncthreads();
    for (int i = blockIdx.x * blockDim.x + t; i < total4;
         i += gridDim.x * blockDim.x) {
        int c = (i / (HW / 4)) & (C - 1);
        float s = s_scale[c], b = s_shift[c];
        float4 v = z[i];
        v.x = fminf(1.f, fmaxf(-1.f, v.x * s + b));
        v.y = fminf(1.f, fmaxf(-1.f, v.y * s + b));
        v.z = fminf(1.f, fmaxf(-1.f, v.z * s + b));
        v.w = fminf(1.f, fmaxf(-1.f, v.w * s + b));
        out[i] = v;
    }
}

// ---------------------------------------------------------------------------
extern "C" void kernel_launch(void* const* d_in, const int* in_sizes, int n_in,
                              void* d_out, int out_size, void* d_ws, size_t ws_size,
                              hipStream_t stream) {
    const float* x  = (const float*)d_in[0];
    const float* w1 = (const float*)d_in[1];
    const float* w2 = (const float*)d_in[2];
    const float* g1 = (const float*)d_in[3];
    const float* b1 = (const float*)d_in[4];
    const float* g2 = (const float*)d_in[5];
    const float* b2 = (const float*)d_in[6];
    float* out = (float*)d_out;

    char* ws = (char*)d_ws;
    size_t off = 0;
    float* z2 = (float*)(ws + off);          off += (size_t)TOTAL * 4;            // 51.4 MB
    uint64_t* xb1 = (uint64_t*)(ws + off);   off += (size_t)NB * HW * WORDS * 8;  // 1.6 MB
    uint64_t* xb2 = (uint64_t*)(ws + off);   off += (size_t)NB * HW * WORDS * 8;
    uint64_t* wb1 = (uint64_t*)(ws + off);   off += (size_t)C * 9 * WORDS * 8;    // 73 KB
    uint64_t* wb2 = (uint64_t*)(ws + off);   off += (size_t)C * 9 * WORDS * 8;
    int* P1 = (int*)(ws + off);              off += (size_t)C * 9 * 4;
    int* P2 = (int*)(ws + off);              off += (size_t)C * 9 * 4;
    double* stats = (double*)(ws + off);     off += 4 * 256 * 8;
    double* sum1 = stats, *sumsq1 = stats + 256, *sum2 = stats + 512, *sumsq2 = stats + 768;

    // y1 (i16) lives in d_out as scratch; fully rewritten by bn_clip at the end
    short* y1 = (short*)d_out;

    // merged pre-pass: both weight packs + x pack + stats zeroing (1 dispatch)
    pack_all_kernel<<<1152 + (NB * HW) / 256, 256, 0, stream>>>(
        w1, w2, x, wb1, wb2, P1, P2, xb1, stats);

    dim3 cgrid(NB * 2, C / COT);   // row-halves x channel-groups = 2048 blocks
    // conv1: y1 (i16) -> d_out scratch, fused BN1 stats
    bconv_kernel<false, short><<<cgrid, 256, 0, stream>>>(xb1, wb1, P1, nullptr, y1, sum1, sumsq1);
    // finalize1 (inline) + BN1 + hardtanh + binarize -> bit-pack
    bn_signpack_kernel<<<(NB * HW + 255) / 256, 256, 0, stream>>>(y1, sum1, sumsq1, g1, b1, xb2);
    // conv2 + residual, fused BN2 stats, z2 -> ws
    bconv_kernel<true, float><<<cgrid, 256, 0, stream>>>(xb2, wb2, P2, x, z2, sum2, sumsq2);
    // finalize2 (inline) + BN2 + hardtanh -> out
    bn_clip_kernel<<<4096, 256, 0, stream>>>((const float4*)z2, sum2, sumsq2, g2, b2,
                                             (float4*)out, TOTAL / 4);
}

// Round 3
// 297.059 us; speedup vs baseline: 1.3522x; 1.1613x over previous
//
#include <hip/hip_runtime.h>
#include <stdint.h>

typedef int v4i __attribute__((ext_vector_type(4)));

// Problem constants
constexpr int C     = 256;           // channels (in == out)
constexpr int H     = 28, W = 28;
constexpr int HW    = H * W;         // 784
constexpr int NB    = 64;            // batch
constexpr int GP    = NB * HW;       // 50176 flattened pixels
constexpr int CNT   = GP;            // per-channel reduction count
constexpr int TOTAL = NB * C * HW;   // 12,845,056
constexpr int MT    = 64;            // pixels per block (M-tile)
constexpr int NBLK  = GP / MT;       // 784 blocks, exact
constexpr int LROWS = 128;           // staged pixel rows: gp0-32 .. gp0+95

// ---------------------------------------------------------------------------
// R8 pre-pass (1 dispatch): weight packs for both convs in MFMA B-fragment
// order + activation i8 pack (plane-major) + stats zeroing.
//
// B-frag order for mfma_i32_16x16x64_i8: lane l holds B[k][n] with
// n = l&15, k = (l>>4)*16 + e (16 contiguous k). Global K order = tap-major
// (tp, then ci). Stored so one wave's frag load is 64 lanes x 16B contiguous:
//   wbf[ ((tp*4 + kb)*16 + nt)*64 + l ] (v4i), nt = co/16.
// Activations: xb[ci_chunk][gp][16B] i8 plane-major -> pack writes coalesced
// and bconv staging reads coalesced. +1 -> 0x01, -1 -> 0xFF. Zero-pad = 0x00.
// ---------------------------------------------------------------------------
__global__ void pack_all_kernel(const float* __restrict__ pw1, const float* __restrict__ pw2,
                                const float* __restrict__ x,
                                v4i* __restrict__ wbf1, v4i* __restrict__ wbf2,
                                v4i* __restrict__ xb, double* __restrict__ stats) {
    const int t = threadIdx.x;
    const int bid = blockIdx.x;
    if (bid < 288) {                       // 288*256 = 73728 = 2 * 36864
        const int gid = bid * 256 + t;
        const bool second = (gid >= 36864);
        const float* w = second ? pw2 : pw1;
        v4i* dst       = second ? wbf2 : wbf1;
        const int idx = second ? gid - 36864 : gid;   // ((tp*4+kb)*16+nt)*64+l
        const int l  = idx & 63;
        const int nt = (idx >> 6) & 15;
        const int kb = (idx >> 10) & 3;
        const int tp = idx >> 12;          // 0..8
        const int co  = nt * 16 + (l & 15);
        const int ci0 = kb * 64 + (l >> 4) * 16;
        int b0 = 0, b1 = 0, b2 = 0, b3 = 0;
#pragma unroll
        for (int e = 0; e < 16; ++e) {
            float v = w[((size_t)co * C + ci0 + e) * 9 + tp];
            int b = (v < 0.f) ? 0xFF : 0x01;
            int sh = (e & 3) * 8;
            if (e < 4) b0 |= b << sh; else if (e < 8) b1 |= b << sh;
            else if (e < 12) b2 |= b << sh; else b3 |= b << sh;
        }
        v4i o; o.x = b0; o.y = b1; o.z = b2; o.w = b3;
        dst[idx] = o;
    } else {
        const int gp = (bid - 288) * 256 + t;   // 196 blocks -> 50176 exact
        if (gp < 1024) stats[gp] = 0.0;         // zero sum1/sumsq1/sum2/sumsq2
        const int n = gp / HW, p = gp % HW;
        const float* base = x + (size_t)n * C * HW + p;
#pragma unroll
        for (int ch = 0; ch < 16; ++ch) {
            int b0 = 0, b1 = 0, b2 = 0, b3 = 0;
#pragma unroll
            for (int e = 0; e < 16; ++e) {
                float v = base[(size_t)(ch * 16 + e) * HW];
                int b = (v < 0.f) ? 0xFF : 0x01;
                int sh = (e & 3) * 8;
                if (e < 4) b0 |= b << sh; else if (e < 8) b1 |= b << sh;
                else if (e < 12) b2 |= b << sh; else b3 |= b << sh;
            }
            v4i o; o.x = b0; o.y = b1; o.z = b2; o.w = b3;
            xb[(size_t)ch * GP + gp] = o;
        }
    }
}

// ---------------------------------------------------------------------------
// Fused finalize (redundant per block) + BN + binarize -> i8 plane-major.
// sign(clip(z)) == sign(z); binarize(0)=+1.
// ---------------------------------------------------------------------------
__global__ void bn_signpack_kernel(const short* __restrict__ y,
                                   const double* __restrict__ sum,
                                   const double* __restrict__ sumsq,
                                   const float* __restrict__ gamma,
                                   const float* __restrict__ beta,
                                   v4i* __restrict__ xb) {
    __shared__ float s_scale[C], s_shift[C];
    const int t = threadIdx.x;
    {
        double mean = sum[t] / (double)CNT;
        double var  = sumsq[t] / (double)CNT - mean * mean;
        double inv  = 1.0 / sqrt(var + 1e-5);
        s_scale[t] = (float)inv * gamma[t];
        s_shift[t] = beta[t] - (float)(mean * inv) * gamma[t];
    }
    __syncthreads();
    const int gp = blockIdx.x * 256 + t;    // grid exact: 196 blocks
    const int n = gp / HW, p = gp % HW;
    const short* base = y + (size_t)n * C * HW + p;
#pragma unroll
    for (int ch = 0; ch < 16; ++ch) {
        int b0 = 0, b1 = 0, b2 = 0, b3 = 0;
#pragma unroll
        for (int e = 0; e < 16; ++e) {
            int c = ch * 16 + e;
            float z = (float)base[(size_t)c * HW] * s_scale[c] + s_shift[c];
            int b = (z < 0.f) ? 0xFF : 0x01;
            int sh = (e & 3) * 8;
            if (e < 4) b0 |= b << sh; else if (e < 8) b1 |= b << sh;
            else if (e < 12) b2 |= b << sh; else b3 |= b << sh;
        }
        v4i o; o.x = b0; o.y = b1; o.z = b2; o.w = b3;
        xb[(size_t)ch * GP + gp] = o;
    }
}

// ---------------------------------------------------------------------------
// R8: binary conv as implicit-GEMM on i8 matrix cores.
// Block: 64 pixels x 256 co. 4 waves, wave wn owns cols [wn*64, wn*64+64).
// Stage pixels [gp0-32, gp0+96) x 256ci into LDS (32KB), XOR-swizzled on the
// 16B-chunk index (chunk ^ (row&15)) -> conflict-free ds_read_b128 (T2).
// K-loop: 9 taps x 4 k-blocks of 64; tap = LDS row offset doff = dr*28+dc;
// per-lane border mask zeroes the A-frag (true zero-padding, no correction
// tables). B-frags read straight from L2 (590KB, L2-resident, each byte once
// per block, lane-contiguous 1KB loads). NO barriers in the main loop.
// Fragment layouts: A row=lane&15, k=(lane>>4)*16+e; B col=lane&15, same k;
// C/D col=lane&15, row=(lane>>4)*4+reg (doc-verified, dtype-independent).
// ---------------------------------------------------------------------------

#define ACC_DECL v4i c00={0,0,0,0},c01={0,0,0,0},c02={0,0,0,0},c03={0,0,0,0}, \
                     c10={0,0,0,0},c11={0,0,0,0},c12={0,0,0,0},c13={0,0,0,0}, \
                     c20={0,0,0,0},c21={0,0,0,0},c22={0,0,0,0},c23={0,0,0,0}, \
                     c30={0,0,0,0},c31={0,0,0,0},c32={0,0,0,0},c33={0,0,0,0};

#define MFMA(a,b,c) c = __builtin_amdgcn_mfma_i32_16x16x64_i8(a, b, c, 0, 0, 0);

#define KSTEP(kb) { \
    const int cb = (kb)*4 + lhi; \
    v4i a0 = xl[lr0*16 + (cb ^ (lr0 & 15))]; a0 &= vm0; \
    v4i a1 = xl[lr1*16 + (cb ^ (lr1 & 15))]; a1 &= vm1; \
    v4i a2 = xl[lr2*16 + (cb ^ (lr2 & 15))]; a2 &= vm2; \
    v4i a3 = xl[lr3*16 + (cb ^ (lr3 & 15))]; a3 &= vm3; \
    v4i b0 = wbf[bb + (kb)*1024]; \
    v4i b1 = wbf[bb + (kb)*1024 + 64]; \
    v4i b2 = wbf[bb + (kb)*1024 + 128]; \
    v4i b3 = wbf[bb + (kb)*1024 + 192]; \
    MFMA(a0,b0,c00) MFMA(a0,b1,c01) MFMA(a0,b2,c02) MFMA(a0,b3,c03) \
    MFMA(a1,b0,c10) MFMA(a1,b1,c11) MFMA(a1,b2,c12) MFMA(a1,b3,c13) \
    MFMA(a2,b0,c20) MFMA(a2,b1,c21) MFMA(a2,b2,c22) MFMA(a2,b3,c23) \
    MFMA(a3,b0,c30) MFMA(a3,b1,c31) MFMA(a3,b2,c32) MFMA(a3,b3,c33) }

// epilogue: one C value (frag (mt,ntl), element j/F) -> store + stats
#define EPIJ(mt,ntl,j,F) { \
    const int gpv = gp0 + (mt)*16 + lhi*4 + (j); \
    const int nn = gpv / HW; const int pp = gpv - nn * HW; \
    const size_t idx = (size_t)nn*(C*HW) + (size_t)(wn*64 + (ntl)*16 + llo)*HW + pp; \
    float yv = (float)(c##mt##ntl.F); \
    if (HAS_RES) yv += residual[idx]; \
    yout[idx] = (OUT_T)yv; \
    sy##ntl += yv; sq##ntl += yv * yv; }
#define EPI(mt,ntl) EPIJ(mt,ntl,0,x) EPIJ(mt,ntl,1,y) EPIJ(mt,ntl,2,z) EPIJ(mt,ntl,3,w)

#define REDN(ntl) { float s1 = sy##ntl, s2 = sq##ntl; \
    s1 += __shfl_down(s1, 32); s1 += __shfl_down(s1, 16); \
    s2 += __shfl_down(s2, 32); s2 += __shfl_down(s2, 16); \
    if (l < 16) { const int co = wn*64 + (ntl)*16 + l; \
        atomicAdd(&sum[co], (double)s1); atomicAdd(&sumsq[co], (double)s2); } }

template<bool HAS_RES, typename OUT_T>
__launch_bounds__(256, 3)
__global__ void bconv_mfma(const v4i* __restrict__ xb,
                           const v4i* __restrict__ wbf,
                           const float* __restrict__ residual,
                           OUT_T* __restrict__ yout,
                           double* __restrict__ sum, double* __restrict__ sumsq) {
    __shared__ v4i xl[LROWS * 16];          // 32768 B
    const int t   = threadIdx.x;
    const int gp0 = blockIdx.x * MT;

    // stage 128 pixel-rows x 16 chunks, coalesced reads, swizzled LDS writes
#pragma unroll
    for (int pass = 0; pass < 8; ++pass) {
        const int i = pass * 256 + t;
        const int c = i >> 7;               // plane 0..15
        const int r = i & 127;              // local row
        int gsrc = gp0 - 32 + r;
        gsrc = min(max(gsrc, 0), GP - 1);   // clamped rows only read via masked taps
        xl[r * 16 + (c ^ (r & 15))] = xb[(size_t)c * GP + gsrc];
    }
    __syncthreads();

    const int l = t & 63, wn = t >> 6;
    const int llo = l & 15, lhi = l >> 4;

    // per-m-tile pixel coords (pixel row of A-frag = llo)
    const int gx0 = gp0 +  0 + llo, gx1 = gp0 + 16 + llo,
              gx2 = gp0 + 32 + llo, gx3 = gp0 + 48 + llo;
    const int pm0 = gx0 % HW, pm1 = gx1 % HW, pm2 = gx2 % HW, pm3 = gx3 % HW;
    const int rm0 = pm0 / W, rm1 = pm1 / W, rm2 = pm2 / W, rm3 = pm3 / W;
    const int cm0 = pm0 % W, cm1 = pm1 % W, cm2 = pm2 % W, cm3 = pm3 % W;

    ACC_DECL

    for (int tp = 0; tp < 9; ++tp) {
        const int dr = tp / 3 - 1, dc = tp % 3 - 1;
        const int doff = dr * W + dc;
        const int m0 = ((unsigned)(cm0 + dc) < 28u && (unsigned)(rm0 + dr) < 28u) ? -1 : 0;
        const int m1 = ((unsigned)(cm1 + dc) < 28u && (unsigned)(rm1 + dr) < 28u) ? -1 : 0;
        const int m2 = ((unsigned)(cm2 + dc) < 28u && (unsigned)(rm2 + dr) < 28u) ? -1 : 0;
        const int m3 = ((unsigned)(cm3 + dc) < 28u && (unsigned)(rm3 + dr) < 28u) ? -1 : 0;
        const v4i vm0 = {m0,m0,m0,m0}, vm1 = {m1,m1,m1,m1},
                  vm2 = {m2,m2,m2,m2}, vm3 = {m3,m3,m3,m3};
        const int lrb = 32 + llo + doff;
        const int lr0 = lrb, lr1 = lrb + 16, lr2 = lrb + 32, lr3 = lrb + 48;
        const int bb = tp * 4096 + wn * 256 + l;
        KSTEP(0) KSTEP(1) KSTEP(2) KSTEP(3)
    }

    // ---- epilogue: store + per-channel stats (fp32 partials, fp64 atomics) --
    float sy0 = 0, sy1 = 0, sy2 = 0, sy3 = 0;
    float sq0 = 0, sq1 = 0, sq2 = 0, sq3 = 0;
    EPI(0,0) EPI(0,1) EPI(0,2) EPI(0,3)
    EPI(1,0) EPI(1,1) EPI(1,2) EPI(1,3)
    EPI(2,0) EPI(2,1) EPI(2,2) EPI(2,3)
    EPI(3,0) EPI(3,1) EPI(3,2) EPI(3,3)
    REDN(0) REDN(1) REDN(2) REDN(3)
}

// ---------------------------------------------------------------------------
// Final: fused finalize (redundant per block) + out = clip(z*s+b, -1, 1)
// ---------------------------------------------------------------------------
__global__ void bn_clip_kernel(const float4* __restrict__ z,
                               const double* __restrict__ sum,
                               const double* __restrict__ sumsq,
                               const float* __restrict__ gamma,
                               const float* __restrict__ beta,
                               float4* __restrict__ out, int total4) {
    __shared__ float s_scale[C], s_shift[C];
    const int t = threadIdx.x;
    {
        double mean = sum[t] / (double)CNT;
        double var  = sumsq[t] / (double)CNT - mean * mean;
        double inv  = 1.0 / sqrt(var + 1e-5);
        s_scale[t] = (float)inv * gamma[t];
        s_shift[t] = beta[t] - (float)(mean * inv) * gamma[t];
    }
    __syncthreads();
    for (int i = blockIdx.x * blockDim.x + t; i < total4;
         i += gridDim.x * blockDim.x) {
        int c = (i / (HW / 4)) & (C - 1);
        float s = s_scale[c], b = s_shift[c];
        float4 v = z[i];
        v.x = fminf(1.f, fmaxf(-1.f, v.x * s + b));
        v.y = fminf(1.f, fmaxf(-1.f, v.y * s + b));
        v.z = fminf(1.f, fmaxf(-1.f, v.z * s + b));
        v.w = fminf(1.f, fmaxf(-1.f, v.w * s + b));
        out[i] = v;
    }
}

// ---------------------------------------------------------------------------
extern "C" void kernel_launch(void* const* d_in, const int* in_sizes, int n_in,
                              void* d_out, int out_size, void* d_ws, size_t ws_size,
                              hipStream_t stream) {
    const float* x  = (const float*)d_in[0];
    const float* w1 = (const float*)d_in[1];
    const float* w2 = (const float*)d_in[2];
    const float* g1 = (const float*)d_in[3];
    const float* b1 = (const float*)d_in[4];
    const float* g2 = (const float*)d_in[5];
    const float* b2 = (const float*)d_in[6];
    float* out = (float*)d_out;

    char* ws = (char*)d_ws;
    size_t off = 0;
    float* z2 = (float*)(ws + off);   off += (size_t)TOTAL * 4;        // 51.4 MB
    v4i* xb1  = (v4i*)(ws + off);     off += (size_t)GP * 16 * 16;     // 12.85 MB
    v4i* xb2  = (v4i*)(ws + off);     off += (size_t)GP * 16 * 16;     // 12.85 MB
    v4i* wbf1 = (v4i*)(ws + off);     off += (size_t)36864 * 16;       // 590 KB
    v4i* wbf2 = (v4i*)(ws + off);     off += (size_t)36864 * 16;
    double* stats = (double*)(ws + off); off += 4 * 256 * 8;
    double* sum1 = stats, *sumsq1 = stats + 256, *sum2 = stats + 512, *sumsq2 = stats + 768;

    // y1 (i16) lives in d_out as scratch; fully rewritten by bn_clip at the end
    short* y1 = (short*)d_out;

    // pre-pass: both weight packs (B-frag order) + x pack (i8 planes) + stats zero
    pack_all_kernel<<<288 + GP / 256, 256, 0, stream>>>(w1, w2, x, wbf1, wbf2, xb1, stats);

    // conv1: y1 (i16) -> d_out scratch, fused BN1 stats
    bconv_mfma<false, short><<<NBLK, 256, 0, stream>>>(xb1, wbf1, nullptr, y1, sum1, sumsq1);
    // finalize1 (inline) + BN1 + hardtanh + binarize -> i8 planes
    bn_signpack_kernel<<<GP / 256, 256, 0, stream>>>(y1, sum1, sumsq1, g1, b1, xb2);
    // conv2 + residual, fused BN2 stats, z2 -> ws
    bconv_mfma<true, float><<<NBLK, 256, 0, stream>>>(xb2, wbf2, x, z2, sum2, sumsq2);
    // finalize2 (inline) + BN2 + hardtanh -> out
    bn_clip_kernel<<<4096, 256, 0, stream>>>((const float4*)z2, sum2, sumsq2, g2, b2,
                                             (float4*)out, TOTAL / 4);
}